// Round 8
// baseline (1514.359 us; speedup 1.0000x reference)
//
#include <hip/hip_runtime.h>
#include <hip/hip_fp16.h>
#include <string.h>

typedef float f32x4 __attribute__((ext_vector_type(4)));

#define B_ 64
#define S_ 128
#define H_ 512
#define NBLK 256        // gru: 8 btiles x 32 i-groups (16 i each)
#define GUARD_MAX (1 << 17)

// ---------------------------------------------------------------------------
// Round 8: split the work.
//  xgemm (parallel, 256 blk x 512 thr): xg[s][b][1536] = emb[dec] @ wih^T + bih
//    for ALL (b,s) up front. n-gate fp32 -> out[b][s][512+i] (context half is
//    dead until attn); r,z packed f16x2 -> xgrz ws (16 MB, ws>=16MB evidenced
//    by round 1). Removes emb HBM latency + x-wave VALU contention from the
//    recurrence entirely.
//  gru_seq (persistent, 256 blk x 512 thr, 112 KB LDS -> 1 blk/CU):
//    8 btiles x 8 batches; block = (bt, ig): i0 = ig*16. ALL 8 waves compute
//    the h-matvec (wave w owns i-pair 2w). Per step: compute -> barrier A
//    (drains sc0sc1 h-stores) -> 1 token/block -> wave0 polls btile's 32
//    tokens (128B coalesced) -> LDS go relay -> all waves stage 16KB h tile
//    -> barrier B. Stage volume/block halved vs round 7; poll set 32.
//  attn_tiled: unchanged (round-7 proven).
// Workspace: xgrz 16 MB + bar[256] int (memset at launch).
// ---------------------------------------------------------------------------

__device__ __forceinline__ int swzW(int k4) { return k4 ^ ((k4 >> 4) & 7); }
// h_s [8][512]: reads (row 2bp/2bp+1, k4=8q+c) and writes (row r, k4=c0/c0+64)
// both resolve to 2-way (free) with this mix of row and k4-bit3.
__device__ __forceinline__ int swzH2(int r, int k4) {
  return k4 ^ ((r >> 1) & 3) ^ (((k4 >> 3) & 1) << 2);
}
// xgemm LDS [32][512]: stage writes (row fixed, k4=m*16+c) and matvec reads
// (rows 2bp.., k4=q*16+c) both 2-way with row+k4-bit3 mixing.
__device__ __forceinline__ int swzXS(int r, int k4) {
  return k4 ^ ((k4 >> 3) & 7) ^ ((r >> 1) & 7);
}

// ---------------------------------------------------------------------------
__global__ __launch_bounds__(512, 2) void xgemm(
    const int*   __restrict__ dec,   // [64][128]
    const float* __restrict__ emb,   // [32000][512]
    const float* __restrict__ wih,   // [1536][512]
    const float* __restrict__ bih,   // [1536]
    float* __restrict__ out,         // [64][128][1024]: xn -> [512+i]
    unsigned int* __restrict__ xgrz) // [64][128][512] f16x2 (r,z)
{
  __shared__ __align__(16) float xs[32 * 512];   // 64 KB
  f32x4* xs4 = (f32x4*)xs;
  const int tid = threadIdx.x;
  const int b  = blockIdx.x >> 2;
  const int sg = blockIdx.x & 3;     // 32-step group

  // stage 32 emb rows (coalesced global, swizzled LDS)
  {
    const int r = tid >> 4, c = tid & 15;
    const int tok = dec[b * S_ + sg * 32 + r];
    const f32x4* src = (const f32x4*)(emb + (size_t)tok * H_);
    #pragma unroll
    for (int m = 0; m < 8; ++m) {
      const int k4 = m * 16 + c;
      xs4[r * 128 + swzXS(r, k4)] = src[k4];
    }
  }
  __syncthreads();

  const int lane = tid & 63, wave = tid >> 6;
  const int bp = lane & 7, q = lane >> 3;     // bp: s-pair, q: 64f k-chunk
  const int kq = q * 16;
  const int r0 = 2 * bp, r1 = r0 + 1, r2 = 16 + r0, r3 = r2 + 1;
  const float4* w4 = (const float4*)wih;

  for (int og = wave * 32; og < wave * 32 + 32; ++og) {
    float a[4][2][3] = {};   // [tok][i-of-pair][gate]
    #pragma unroll 4
    for (int c = 0; c < 16; ++c) {
      const int k4 = kq + c;
      const f32x4 x0 = xs4[r0 * 128 + swzXS(r0, k4)];
      const f32x4 x1 = xs4[r1 * 128 + swzXS(r1, k4)];
      const f32x4 x2 = xs4[r2 * 128 + swzXS(r2, k4)];
      const f32x4 x3 = xs4[r3 * 128 + swzXS(r3, k4)];
      #pragma unroll
      for (int g = 0; g < 3; ++g) {
        #pragma unroll
        for (int e = 0; e < 2; ++e) {
          const float4 wv = w4[(size_t)(g * 512 + og * 2 + e) * 128 + k4];
          a[0][e][g] = fmaf(x0.x, wv.x, fmaf(x0.y, wv.y,
                       fmaf(x0.z, wv.z, fmaf(x0.w, wv.w, a[0][e][g]))));
          a[1][e][g] = fmaf(x1.x, wv.x, fmaf(x1.y, wv.y,
                       fmaf(x1.z, wv.z, fmaf(x1.w, wv.w, a[1][e][g]))));
          a[2][e][g] = fmaf(x2.x, wv.x, fmaf(x2.y, wv.y,
                       fmaf(x2.z, wv.z, fmaf(x2.w, wv.w, a[2][e][g]))));
          a[3][e][g] = fmaf(x3.x, wv.x, fmaf(x3.y, wv.y,
                       fmaf(x3.z, wv.z, fmaf(x3.w, wv.w, a[3][e][g]))));
        }
      }
    }
    #pragma unroll
    for (int t = 0; t < 4; ++t)
      #pragma unroll
      for (int e = 0; e < 2; ++e)
        #pragma unroll
        for (int g = 0; g < 3; ++g) {
          float v = a[t][e][g];
          v += __shfl_xor(v, 8); v += __shfl_xor(v, 16); v += __shfl_xor(v, 32);
          a[t][e][g] = v;
        }
    {
      const int tk = q >> 1, e = q & 1;      // all 8 q-lanes write one combo
      const int sl = (tk >> 1) * 16 + 2 * bp + (tk & 1);
      const int i  = og * 2 + e;
      const float ar = a[tk][e][0] + bih[i];
      const float az = a[tk][e][1] + bih[512 + i];
      const float an = a[tk][e][2] + bih[1024 + i];
      __half2 h2; h2.x = __float2half(ar); h2.y = __float2half(az);
      const size_t tb = (size_t)b * S_ + sg * 32 + sl;
      unsigned int u; memcpy(&u, &h2, 4);
      xgrz[tb * 512 + i] = u;
      out[tb * 1024 + 512 + i] = an;
    }
  }
}

// ---------------------------------------------------------------------------
__global__ __launch_bounds__(512, 2) void gru_seq(
    const float* __restrict__ eh,    // [64][512]
    const float* __restrict__ whh,   // [1536][512]
    const float* __restrict__ bhh,   // [1536]
    float* __restrict__ out,         // [64][128][1024]
    const unsigned int* __restrict__ xgrz,
    int* __restrict__ bar)           // [256] one token per block
{
  __shared__ __align__(16) float whh_s[48 * 512];  // 96 KB (rows g*16+il)
  __shared__ __align__(16) float h_s[8 * 512];     // 16 KB
  __shared__ int go_w;
  volatile int* gop = &go_w;

  const int tid  = threadIdx.x;
  const int wave = tid >> 6;
  const int lane = tid & 63;
  const int bp   = lane & 3;        // batch-pair 0..3 (batches 2bp, 2bp+1)
  const int q    = lane >> 2;       // k-chunk 0..15 (32 floats each)
  const int bt   = blockIdx.x >> 5; // 8 btiles x 8 batches
  const int ig   = blockIdx.x & 31;
  const int i0   = ig * 16;
  const int b0g  = bt * 8;
  const int ilA  = 2 * wave;        // this wave's i-pair
  const int bsel = (q >> 1) & 1, ilsel = q & 1;
  const int my_b  = 2 * bp + bsel;
  const int my_il = ilA + ilsel;
  const int my_i  = i0 + my_il;

  f32x4* whh4 = (f32x4*)whh_s;
  f32x4* h4   = (f32x4*)h_s;

  if (tid == 0) *gop = 0;

  // stage whh slice (48 rows) into LDS once
  {
    const int f4 = tid & 127, rb = tid >> 7;     // rb 0..3
    #pragma unroll
    for (int m = 0; m < 12; ++m) {
      const int lr = rb + 4 * m;                 // 0..47 = g*16 + il
      const int g = lr >> 4, il = lr & 15;
      whh4[lr * 128 + swzW(f4)] =
          ((const f32x4*)whh)[(size_t)(g * 512 + i0 + il) * 128 + f4];
    }
  }

  float b_hr = 0, b_hz = 0, b_hn = 0;
  if (q < 4) {
    b_hr = bhh[my_i]; b_hz = bhh[512 + my_i]; b_hn = bhh[1024 + my_i];
  }

  // prelude: h(-1) = eh into LDS
  {
    const int r = tid >> 6, c0 = tid & 63;
    const f32x4* src = (const f32x4*)(eh + (size_t)(b0g + r) * H_);
    h4[r * 128 + swzH2(r, c0)]      = src[c0];
    h4[r * 128 + swzH2(r, c0 + 64)] = src[c0 + 64];
  }
  __syncthreads();

  const int br0 = 2 * bp, br1 = br0 + 1;
  const int kq = q * 8;                        // f4 base of 32-float chunk

  for (int s = 0; s < S_; ++s) {
    // prefetch x-gates (independent of h_s; latency hides under matvec)
    float xn_v = 0.f; unsigned int rz_v = 0;
    if (q < 4) {
      const size_t tb = (size_t)(b0g + my_b) * S_ + s;
      xn_v = out[tb * 1024 + 512 + my_i];
      rz_v = xgrz[tb * 512 + my_i];
    }

    // h-side matvec from LDS (all 8 waves)
    float a[2][2][3] = {};
    #pragma unroll
    for (int c = 0; c < 8; ++c) {
      const int k4 = kq + c;
      const f32x4 hv0 = h4[br0 * 128 + swzH2(br0, k4)];
      const f32x4 hv1 = h4[br1 * 128 + swzH2(br1, k4)];
      const int ws = swzW(k4);
      #pragma unroll
      for (int g = 0; g < 3; ++g) {
        #pragma unroll
        for (int e = 0; e < 2; ++e) {
          const f32x4 wv = whh4[(g * 16 + ilA + e) * 128 + ws];
          a[0][e][g] = fmaf(hv0.x, wv.x, fmaf(hv0.y, wv.y,
                       fmaf(hv0.z, wv.z, fmaf(hv0.w, wv.w, a[0][e][g]))));
          a[1][e][g] = fmaf(hv1.x, wv.x, fmaf(hv1.y, wv.y,
                       fmaf(hv1.z, wv.z, fmaf(hv1.w, wv.w, a[1][e][g]))));
        }
      }
    }
    #pragma unroll
    for (int bb = 0; bb < 2; ++bb)
      #pragma unroll
      for (int e = 0; e < 2; ++e)
        #pragma unroll
        for (int g = 0; g < 3; ++g) {
          float v = a[bb][e][g];
          v += __shfl_xor(v, 4);  v += __shfl_xor(v, 8);
          v += __shfl_xor(v, 16); v += __shfl_xor(v, 32);
          a[bb][e][g] = v;
        }

    if (q < 4) {
      __half2 rz; memcpy(&rz, &rz_v, 4);
      const float ir  = __half2float(rz.x);
      const float iz  = __half2float(rz.y);
      const float hr = a[bsel][ilsel][0] + b_hr;
      const float hz = a[bsel][ilsel][1] + b_hz;
      const float hn = a[bsel][ilsel][2] + b_hn;
      const float rr = 1.f / (1.f + expf(-(ir + hr)));
      const float zz = 1.f / (1.f + expf(-(iz + hz)));
      const float nn = tanhf(xn_v + rr * hn);
      const int f4a = my_b * 128 + swzH2(my_b, my_i >> 2);
      const float hold = h_s[f4a * 4 + (my_i & 3)];
      const float hnew = (1.f - zz) * nn + zz * hold;
      const float hpart = __shfl_xor(hnew, 4);   // partner: ilsel^1, same b
      if ((q & 1) == 0) {
        float2 hv2 = make_float2(hnew, hpart);
        unsigned long long u; memcpy(&u, &hv2, 8);
        __hip_atomic_store(
            (unsigned long long*)(out + ((size_t)(b0g + my_b) * S_ + s) * 1024
                                  + i0 + ilA),
            u, __ATOMIC_RELAXED, __HIP_MEMORY_SCOPE_AGENT);
      }
    }

    __syncthreads();   // A: per-wave vmcnt(0) before barrier -> h published
    if (s + 1 == S_) break;

    if (tid == 0)
      __hip_atomic_store(bar + blockIdx.x, s + 1,
                         __ATOMIC_RELAXED, __HIP_MEMORY_SCOPE_AGENT);
    if (wave == 0) {
      const int* tp = bar + bt * 32 + (lane & 31);   // btile's 32 tokens
      int tk, g2 = 0;
      do {
        asm volatile(
            "global_load_dword %0, %1, off sc0 sc1\n\t"
            "s_waitcnt vmcnt(0)"
            : "=v"(tk) : "v"(tp) : "memory");
      } while (!__all(tk > s) && ++g2 < GUARD_MAX);
      if (lane == 0) *gop = s + 1;
    } else {
      int g2 = 0;
      while (*gop < s + 1 && ++g2 < GUARD_MAX) {}
    }
    __builtin_amdgcn_sched_barrier(0);

    // stage h(s): all 512 threads, 16 KB, coalesced sc0 sc1
    {
      const int r = tid >> 6, c0 = tid & 63;
      const float* base = out + ((size_t)(b0g + r) * S_ + s) * 1024 + c0 * 4;
      f32x4 t0, t1;
      asm volatile(
          "global_load_dwordx4 %0, %2, off sc0 sc1\n\t"
          "global_load_dwordx4 %1, %2, off offset:1024 sc0 sc1\n\t"
          "s_waitcnt vmcnt(0)"
          : "=&v"(t0), "=&v"(t1) : "v"(base) : "memory");
      h4[r * 128 + swzH2(r, c0)]      = t0;
      h4[r * 128 + swzH2(r, c0 + 64)] = t1;
    }
    __syncthreads();   // B: h_s = h(s)
  }
}

// ---------------------------------------------------------------------------
// attn_tiled: unchanged from round 7 (proven).
__global__ __launch_bounds__(256) void attn_tiled(
    const float* __restrict__ enc,   // [64][128][512]
    float* __restrict__ out)         // [64][128][1024]
{
  __shared__ __align__(16) float enc_s[32 * 512];
  __shared__ __align__(16) float hsm[8 * 512];
  __shared__ float pp[8][128];

  const int tid = threadIdx.x;
  const int b  = blockIdx.x & 63;
  const int sg = blockIdx.x >> 6;
  float4* es4  = (float4*)enc_s;
  float4* hsm4 = (float4*)hsm;

  {
    const int j = tid >> 5, il = tid & 31;
    const float4* hsrc =
        (const float4*)(out + ((size_t)b * S_ + sg * 8 + j) * 1024);
    #pragma unroll
    for (int m = 0; m < 4; ++m) {
      const int k4 = il + 32 * m;
      hsm4[j * 128 + swzW(k4)] = hsrc[k4];
    }
  }
  __syncthreads();

  const int srl = tid >> 3, q8 = tid & 7;
  for (int T = 0; T < 4; ++T) {
    {
      const float4* esrc = (const float4*)(enc + ((size_t)b * S_ + T * 32) * H_);
      #pragma unroll
      for (int m = 0; m < 16; ++m) {
        const int idx = tid + 256 * m;
        const int row = idx >> 7, k4 = idx & 127;
        es4[row * 128 + swzW(k4)] = esrc[row * 128 + k4];
      }
    }
    __syncthreads();
    float acc[8] = {};
    #pragma unroll 4
    for (int c = 0; c < 16; ++c) {
      const int ws = swzW(q8 * 16 + c);
      const float4 ev = es4[srl * 128 + ws];
      #pragma unroll
      for (int j = 0; j < 8; ++j) {
        const float4 hv = hsm4[j * 128 + ws];
        acc[j] = fmaf(ev.x, hv.x, fmaf(ev.y, hv.y,
                 fmaf(ev.z, hv.z, fmaf(ev.w, hv.w, acc[j]))));
      }
    }
    #pragma unroll
    for (int j = 0; j < 8; ++j) {
      acc[j] += __shfl_xor(acc[j], 1);
      acc[j] += __shfl_xor(acc[j], 2);
      acc[j] += __shfl_xor(acc[j], 4);
    }
    if (q8 == 0) {
      #pragma unroll
      for (int j = 0; j < 8; ++j) pp[j][T * 32 + srl] = acc[j];
    }
    __syncthreads();
  }

  {
    const int jg = tid >> 5, l = tid & 31;
    float v0 = pp[jg][l], v1 = pp[jg][l + 32],
          v2 = pp[jg][l + 64], v3 = pp[jg][l + 96];
    float mx = fmaxf(fmaxf(v0, v1), fmaxf(v2, v3));
    #pragma unroll
    for (int o = 16; o > 0; o >>= 1) mx = fmaxf(mx, __shfl_xor(mx, o));
    const float e0 = expf(v0 - mx), e1 = expf(v1 - mx),
                e2 = expf(v2 - mx), e3 = expf(v3 - mx);
    float sm = e0 + e1 + e2 + e3;
    #pragma unroll
    for (int o = 16; o > 0; o >>= 1) sm += __shfl_xor(sm, o);
    const float inv = 1.f / sm;
    pp[jg][l] = e0 * inv; pp[jg][l + 32] = e1 * inv;
    pp[jg][l + 64] = e2 * inv; pp[jg][l + 96] = e3 * inv;
  }
  __syncthreads();

  {
    const int j = tid >> 5, il = tid & 31;
    const float* ecol = enc + (size_t)b * (S_ * H_) + il * 16;
    const float* prow = pp[j];
    float4 c0 = {0,0,0,0}, c1 = {0,0,0,0}, c2 = {0,0,0,0}, c3 = {0,0,0,0};
    #pragma unroll 4
    for (int sr = 0; sr < S_; ++sr) {
      const float p = prow[sr];
      const float4* er = (const float4*)(ecol + (size_t)sr * H_);
      const float4 u0 = er[0], u1 = er[1], u2 = er[2], u3 = er[3];
      c0.x = fmaf(p, u0.x, c0.x); c0.y = fmaf(p, u0.y, c0.y);
      c0.z = fmaf(p, u0.z, c0.z); c0.w = fmaf(p, u0.w, c0.w);
      c1.x = fmaf(p, u1.x, c1.x); c1.y = fmaf(p, u1.y, c1.y);
      c1.z = fmaf(p, u1.z, c1.z); c1.w = fmaf(p, u1.w, c1.w);
      c2.x = fmaf(p, u2.x, c2.x); c2.y = fmaf(p, u2.y, c2.y);
      c2.z = fmaf(p, u2.z, c2.z); c2.w = fmaf(p, u2.w, c2.w);
      c3.x = fmaf(p, u3.x, c3.x); c3.y = fmaf(p, u3.y, c3.y);
      c3.z = fmaf(p, u3.z, c3.z); c3.w = fmaf(p, u3.w, c3.w);
    }
    float4* dst = (float4*)(out + ((size_t)b * S_ + sg * 8 + j) * 1024 +
                            512 + il * 16);
    dst[0] = c0; dst[1] = c1; dst[2] = c2; dst[3] = c3;
  }
}

// ---------------------------------------------------------------------------
extern "C" void kernel_launch(void* const* d_in, const int* in_sizes, int n_in,
                              void* d_out, int out_size, void* d_ws, size_t ws_size,
                              hipStream_t stream) {
  (void)in_sizes; (void)n_in; (void)out_size; (void)ws_size;
  const int*   dec = (const int*)d_in[0];
  const float* eh  = (const float*)d_in[1];
  const float* enc = (const float*)d_in[2];
  const float* emb = (const float*)d_in[3];
  const float* wih = (const float*)d_in[4];
  const float* whh = (const float*)d_in[5];
  const float* bih = (const float*)d_in[6];
  const float* bhh = (const float*)d_in[7];
  float* out = (float*)d_out;
  unsigned int* xgrz = (unsigned int*)d_ws;               // 16 MB
  int* bar = (int*)((char*)d_ws + (16u << 20));           // 1 KB tokens

  hipMemsetAsync(bar, 0, NBLK * sizeof(int), stream);
  xgemm<<<NBLK, 512, 0, stream>>>(dec, emb, wih, bih, out, xgrz);
  gru_seq<<<NBLK, 512, 0, stream>>>(eh, whh, bhh, out, xgrz, bar);
  attn_tiled<<<16 * B_, 256, 0, stream>>>(enc, out);
}